// Round 5
// baseline (4260.682 us; speedup 1.0000x reference)
//
#include <hip/hip_runtime.h>
#include <hip/hip_fp16.h>
#include <cstdint>
#include <cstddef>

typedef _Float16 f16;
typedef __attribute__((ext_vector_type(8))) _Float16 f16x8;
typedef __attribute__((ext_vector_type(4))) _Float16 f16x4;
typedef __attribute__((ext_vector_type(2))) _Float16 f16x2;
typedef __attribute__((ext_vector_type(4))) float f32x4;

#define B_SZ 256
#define T_IN 1024
#define W_CH 512
#define U_N  512
#define P_K  16
#define TP   1009            // T_IN - P_K + 1
#define MROWS (B_SZ * TP)    // 258304

// ---------------------------------------------------------------------------
// Weight convert + transpose: fp32 [k][n] -> f16 [n][k].
// Kt: canonical k order (used by k_gemm).
// Rt: k-axis PERMUTED with pi(k) = (k & ~63) | ((k&15)<<2) | ((k>>4)&3) so the
// rnn state writes to LDS become contiguous stores. MFMA result is invariant
// to a shared k-permutation of A and B.
// ---------------------------------------------------------------------------
__global__ __launch_bounds__(256) void k_convert(
    const float* __restrict__ kern, const float* __restrict__ rec,
    f16* __restrict__ Kt, f16* __restrict__ Rt) {
  int idx = blockIdx.x * 256 + threadIdx.x;   // 0 .. 2*2^18
  int which = idx >> 18;
  int e = idx & 262143;
  int n = e >> 9;
  int k = e & 511;
  if (which == 0) {
    Kt[(size_t)n * 512 + k] = (f16)kern[(size_t)k * 512 + n];
  } else {
    int kp = (k & 448) | ((k & 15) << 2) | ((k >> 4) & 3);
    Rt[(size_t)n * 512 + kp] = (f16)rec[(size_t)k * 512 + n];
  }
}

// ---------------------------------------------------------------------------
// PSC conv: syn[b,t,w] = psc_b + sum_k psc_w[k] * x[b,t+k,w]   (f16 out)
// Thread owns (b, w-quad) and marches 64 t's with a 16-deep float4 ring.
// ---------------------------------------------------------------------------
__global__ __launch_bounds__(256) void k_conv(
    const float* __restrict__ x, const float* __restrict__ psc_w,
    const float* __restrict__ psc_b, f16* __restrict__ syn) {
  int g  = blockIdx.x * 256 + threadIdx.x;
  int wq = g & 127;              // w quad (4 floats)
  int tt = (g >> 7) & 15;        // t tile of 64
  int b  = g >> 11;
  int t0 = tt * 64;
  const float4* xr = (const float4*)x + (size_t)b * T_IN * 128 + wq;
  float wgt[16];
#pragma unroll
  for (int k = 0; k < 16; ++k) wgt[k] = psc_w[k];
  float b0 = psc_b[0];
  float4 win[16];
#pragma unroll
  for (int i = 0; i < 15; ++i) win[i] = xr[(size_t)(t0 + i) * 128];
  f16* sp = syn + ((size_t)b * TP + t0) * 512 + wq * 4;
  int steps = TP - t0; if (steps > 64) steps = 64;   // wave-uniform
  for (int j0 = 0; j0 < 64; j0 += 16) {
#pragma unroll
    for (int jj = 0; jj < 16; ++jj) {
      int j = j0 + jj;
      if (j < steps) {
        win[(j + 15) & 15] = xr[(size_t)(t0 + j + 15) * 128];
        float ax = b0, ay = b0, az = b0, aw = b0;
#pragma unroll
        for (int k = 0; k < 16; ++k) {
          float4 v = win[(j + k) & 15];
          float wk = wgt[k];
          ax += wk * v.x; ay += wk * v.y; az += wk * v.z; aw += wk * v.w;
        }
        f16x4 o; o.x = (f16)ax; o.y = (f16)ay; o.z = (f16)az; o.w = (f16)aw;
        *(f16x4*)(sp + (size_t)j * 512) = o;
      }
    }
  }
}

// ---------------------------------------------------------------------------
// Xp = syn @ K + bias  (fp32 result written into d_out, overwritten later by
// the recurrent kernel in place).  128x128 tile, BK=32, mfma 16x16x32 f16.
// ---------------------------------------------------------------------------
__global__ __launch_bounds__(256) void k_gemm(
    const f16* __restrict__ syn, const f16* __restrict__ Kt,
    const float* __restrict__ bias, float* __restrict__ out) {
  int bid = blockIdx.x;
  size_t m0 = (size_t)(bid >> 2) * 128;
  int n0 = (bid & 3) * 128;
  int tid = threadIdx.x;
  int wave = tid >> 6, lane = tid & 63;
  int q = lane >> 4, l15 = lane & 15;
  __shared__ f16 lA[128 * 32];
  __shared__ f16 lB[128 * 32];
  f32x4 acc[8][2] = {};
  int s0 = tid, s1 = tid + 256;
  int rA0 = s0 >> 2, cA0 = (s0 & 3) * 8;
  int rA1 = s1 >> 2, cA1 = (s1 & 3) * 8;
  for (int k0 = 0; k0 < 512; k0 += 32) {
    f16x8 a0 = *(const f16x8*)(syn + (m0 + rA0) * 512 + k0 + cA0);
    f16x8 a1 = *(const f16x8*)(syn + (m0 + rA1) * 512 + k0 + cA1);
    f16x8 b0 = *(const f16x8*)(Kt + (size_t)(n0 + rA0) * 512 + k0 + cA0);
    f16x8 b1 = *(const f16x8*)(Kt + (size_t)(n0 + rA1) * 512 + k0 + cA1);
    __syncthreads();                       // previous tile fully consumed
    *(f16x8*)(lA + s0 * 8) = a0;  *(f16x8*)(lA + s1 * 8) = a1;
    *(f16x8*)(lB + s0 * 8) = b0;  *(f16x8*)(lB + s1 * 8) = b1;
    __syncthreads();
    f16x8 bf[2];
#pragma unroll
    for (int j = 0; j < 2; ++j)
      bf[j] = *(const f16x8*)(lB + (wave * 32 + j * 16 + l15) * 32 + q * 8);
#pragma unroll
    for (int i = 0; i < 8; ++i) {
      f16x8 af = *(const f16x8*)(lA + (i * 16 + l15) * 32 + q * 8);
      acc[i][0] = __builtin_amdgcn_mfma_f32_16x16x32_f16(af, bf[0], acc[i][0], 0, 0, 0);
      acc[i][1] = __builtin_amdgcn_mfma_f32_16x16x32_f16(af, bf[1], acc[i][1], 0, 0, 0);
    }
  }
#pragma unroll
  for (int j = 0; j < 2; ++j) {
    int col = n0 + wave * 32 + j * 16 + l15;
    float bv = bias[col];
#pragma unroll
    for (int i = 0; i < 8; ++i) {
      size_t row = m0 + i * 16 + q * 4;
#pragma unroll
      for (int r = 0; r < 4; ++r)
        out[(row + r) * 512 + col] = acc[i][j][r] + bv;
    }
  }
}

// ---------------------------------------------------------------------------
// Sequential recurrence.  256 blocks x 1 batch, 512 threads (8 waves, 2/SIMD);
// wave owns 64 output units.  R split: kk0..10 register/AGPR-resident,
// kk11..14 in a 128KB swizzled LDS tile, kk15 streamed from L2.
// Round-5 changes:
//  (1) ZERO-LANE af reads: lanes l15>0 read from a permanent zero region of
//      LDS whose bank-quads are disjoint from the real row's quads (offset
//      delta/16 == 4 mod 8).  Replaces the 64 v_and masks per wave with a
//      conflict-free 8-address LDS read.  No VALU in the A path.
//  (2) nt PAIR SPLIT: acc{0,1} computed over all kk, then their epilogue
//      (sigmoid chain + io store + SR half-write) runs WHILE acc{2,3}'s 32
//      MFMAs issue -- only the last pair's epilogue is exposed before the
//      barrier.
// One raw s_barrier per step (lgkmcnt drain only).
// ---------------------------------------------------------------------------
__global__ __launch_bounds__(512, 2) void k_rnn(
    const f16* __restrict__ Rt, float* __restrict__ io) {
  int b = blockIdx.x;             // one batch per block
  int tid = threadIdx.x, wave = tid >> 6, lane = tid & 63;
  int q = lane >> 4, l15 = lane & 15;
  __shared__ f16 R4[4 * 512 * 32];           // kk 11..14, swizzled (128KB)
  // SRZ: [SR0 512][SR1 512][pad 32][Z 544]  (halves).  Z-SR0=2112B (132*16,
  // 132%8=4), Z-SR1=1088B (68*16, 68%8=4): zero-region bank-quads are
  // disjoint from both state buffers' quads -> af reads conflict-free.
  __shared__ __align__(64) f16 SRZ[1600];

  // ---- stage R kk11..14 into LDS, swizzle: 16B slot c -> c ^ (row&3) ----
  {
    int row = tid;                   // 0..511
    const f16x8* src = (const f16x8*)(Rt + (size_t)row * 512 + 11 * 32);
#pragma unroll
    for (int g = 0; g < 4; ++g) {
      char* dst = (char*)R4 + g * 32768 + row * 64;
#pragma unroll
      for (int c = 0; c < 4; ++c)
        *(f16x8*)(dst + ((c * 16) ^ ((row & 3) << 4))) = src[g * 4 + c];
    }
    for (int i = tid; i < 1600; i += 512) SRZ[i] = (f16)0.f;
  }

  const f16* rbase = Rt + (size_t)(wave * 64 + l15) * 512 + q * 8;
  f16x8 rs[11][4];                // kk = 0..10 register/AGPR-resident
#pragma unroll
  for (int kk = 0; kk < 11; ++kk)
#pragma unroll
    for (int nt = 0; nt < 4; ++nt)
      rs[kk][nt] = *(const f16x8*)(rbase + (size_t)nt * 8192 + kk * 32);

  // per-lane R4 read base: row = wave*64 + l15 (+nt*16), slot q ^ (l15&3)
  const char* r4base = (const char*)R4 + (wave * 64 + l15) * 64
                       + ((q * 16) ^ ((l15 & 3) << 4));

  bool l0 = (l15 == 0);
  const f16* zb = SRZ + 1056 + q * 8;            // zero region (never written)
  const f16* pc = l0 ? (SRZ + q * 8)       : zb; // af base, current state buf
  const f16* pn = l0 ? (SRZ + 512 + q * 8) : zb; // af base, next state buf
  f16* wc = SRZ + 512 + wave * 64 + l15 * 4;     // SR write when reading SR0
  f16* wn = SRZ + wave * 64 + l15 * 4;           // SR write when reading SR1

  bool active = (q == 0);         // only C/D row 0 is real
  unsigned ioff = (unsigned)b * (TP * 512u) + (unsigned)(wave * 64 + l15);
  float xp[4];
#pragma unroll
  for (int nt = 0; nt < 4; ++nt) xp[nt] = io[ioff + nt * 16u];

  __syncthreads();

  for (int t = 0; t < TP; ++t) {
    // ---- issue kk15 L2 stream at step-top (consumed late) ----
    f16x8 sw[4];
#pragma unroll
    for (int nt = 0; nt < 4; ++nt)
      sw[nt] = *(const f16x8*)(rbase + (size_t)nt * 8192 + 15 * 32);

    // ================= pair 0: nt 0,1 =================
    f32x4 a0 = {}, a1 = {};
#pragma unroll
    for (int kk = 0; kk < 11; ++kk) {
      f16x8 af = *(const f16x8*)(pc + kk * 32);
      a0 = __builtin_amdgcn_mfma_f32_16x16x32_f16(af, rs[kk][0], a0, 0, 0, 0);
      a1 = __builtin_amdgcn_mfma_f32_16x16x32_f16(af, rs[kk][1], a1, 0, 0, 0);
    }
#pragma unroll
    for (int g = 0; g < 4; ++g) {
      f16x8 bf0 = *(const f16x8*)(r4base + g * 32768);
      f16x8 bf1 = *(const f16x8*)(r4base + g * 32768 + 1024);
      f16x8 af  = *(const f16x8*)(pc + (11 + g) * 32);
      a0 = __builtin_amdgcn_mfma_f32_16x16x32_f16(af, bf0, a0, 0, 0, 0);
      a1 = __builtin_amdgcn_mfma_f32_16x16x32_f16(af, bf1, a1, 0, 0, 0);
    }
    {
      f16x8 af = *(const f16x8*)(pc + 15 * 32);
      a0 = __builtin_amdgcn_mfma_f32_16x16x32_f16(af, sw[0], a0, 0, 0, 0);
      a1 = __builtin_amdgcn_mfma_f32_16x16x32_f16(af, sw[1], a1, 0, 0, 0);
    }
    // ---- epilogue pair 0 (overlaps pair-1 MFMAs below) ----
    {
      float o0 = a0[0] + xp[0];
      float o1 = a1[0] + xp[1];
      float n0 = __builtin_amdgcn_rcpf(1.f + __builtin_amdgcn_exp2f(-4.3280850f * o0));
      float n1 = __builtin_amdgcn_rcpf(1.f + __builtin_amdgcn_exp2f(-4.3280850f * o1));
      float g0 = __builtin_amdgcn_rcpf(1.f + __builtin_amdgcn_exp2f((2.f * n0 - 1.f) * 1.4426950f));
      float g1 = __builtin_amdgcn_rcpf(1.f + __builtin_amdgcn_exp2f((2.f * n1 - 1.f) * 1.4426950f));
      if (active) {
        io[ioff]       = n0;
        io[ioff + 16u] = n1;
        f16x2 sv; sv.x = (f16)(o0 * g0); sv.y = (f16)(o1 * g1);
        *(f16x2*)wc = sv;
      }
    }

    // ================= pair 1: nt 2,3 =================
    f32x4 a2 = {}, a3 = {};
#pragma unroll
    for (int kk = 0; kk < 11; ++kk) {
      f16x8 af = *(const f16x8*)(pc + kk * 32);
      a2 = __builtin_amdgcn_mfma_f32_16x16x32_f16(af, rs[kk][2], a2, 0, 0, 0);
      a3 = __builtin_amdgcn_mfma_f32_16x16x32_f16(af, rs[kk][3], a3, 0, 0, 0);
    }
#pragma unroll
    for (int g = 0; g < 4; ++g) {
      f16x8 bf2 = *(const f16x8*)(r4base + g * 32768 + 2048);
      f16x8 bf3 = *(const f16x8*)(r4base + g * 32768 + 3072);
      f16x8 af  = *(const f16x8*)(pc + (11 + g) * 32);
      a2 = __builtin_amdgcn_mfma_f32_16x16x32_f16(af, bf2, a2, 0, 0, 0);
      a3 = __builtin_amdgcn_mfma_f32_16x16x32_f16(af, bf3, a3, 0, 0, 0);
    }
    {
      f16x8 af = *(const f16x8*)(pc + 15 * 32);
      a2 = __builtin_amdgcn_mfma_f32_16x16x32_f16(af, sw[2], a2, 0, 0, 0);
      a3 = __builtin_amdgcn_mfma_f32_16x16x32_f16(af, sw[3], a3, 0, 0, 0);
    }
    // ---- epilogue pair 1 (exposed tail) ----
    {
      float o2 = a2[0] + xp[2];
      float o3 = a3[0] + xp[3];
      float n2 = __builtin_amdgcn_rcpf(1.f + __builtin_amdgcn_exp2f(-4.3280850f * o2));
      float n3 = __builtin_amdgcn_rcpf(1.f + __builtin_amdgcn_exp2f(-4.3280850f * o3));
      float g2 = __builtin_amdgcn_rcpf(1.f + __builtin_amdgcn_exp2f((2.f * n2 - 1.f) * 1.4426950f));
      float g3 = __builtin_amdgcn_rcpf(1.f + __builtin_amdgcn_exp2f((2.f * n3 - 1.f) * 1.4426950f));
      if (active) {
        io[ioff + 32u] = n2;
        io[ioff + 48u] = n3;
        f16x2 sv; sv.x = (f16)(o2 * g2); sv.y = (f16)(o3 * g3);
        *(f16x2*)(wc + 2) = sv;
      }
    }
    ioff += 512u;
    if (t < TP - 1) {                     // prefetch Xp[t+1]
#pragma unroll
      for (int nt = 0; nt < 4; ++nt) xp[nt] = io[ioff + nt * 16u];
    }
    // Single barrier per step: drain LDS (state write) only; global stores
    // are disjoint-address and never drained in-loop.
    asm volatile("s_waitcnt lgkmcnt(0)\n\ts_barrier" ::: "memory");
    const f16* tp = pc; pc = pn; pn = tp;
    f16* tw = wc; wc = wn; wn = tw;
  }
}

// ---------------------------------------------------------------------------
extern "C" void kernel_launch(void* const* d_in, const int* in_sizes, int n_in,
                              void* d_out, int out_size, void* d_ws, size_t ws_size,
                              hipStream_t stream) {
  (void)in_sizes; (void)n_in; (void)out_size; (void)ws_size;
  const float* x     = (const float*)d_in[0];
  const float* psc_w = (const float*)d_in[1];
  const float* psc_b = (const float*)d_in[2];
  const float* kern  = (const float*)d_in[3];
  const float* rec   = (const float*)d_in[4];
  const float* bias  = (const float*)d_in[5];
  float* out = (float*)d_out;
  char* ws = (char*)d_ws;
  // ws layout: syn f16 (258304*512*2 = 264,503,296 B) | Kt f16 512KB | Rt f16 512KB
  f16* syn = (f16*)ws;
  f16* Kt  = (f16*)(ws + 264503296ull);
  f16* Rt  = (f16*)(ws + 265027584ull);

  k_convert<<<2048, 256, 0, stream>>>(kern, rec, Kt, Rt);
  k_conv   <<<2048, 256, 0, stream>>>(x, psc_w, psc_b, syn);
  k_gemm   <<<2018 * 4, 256, 0, stream>>>(syn, Kt, bias, out);
  k_rnn    <<<256, 512, 0, stream>>>(Rt, out);
}